// Round 8
// baseline (142.629 us; speedup 1.0000x reference)
//
#include <hip/hip_runtime.h>
#include <hip/hip_cooperative_groups.h>

namespace cg = cooperative_groups;

#define NUM_C 1000
#define NUM_A 512
#define PRE_BLOCKS 64
#define PRE_THREADS 1024
#define RED_THREADS 512

typedef float f32x4 __attribute__((ext_vector_type(4)));

// Workspace layout (bytes):
//   [0,      4096)   starts[1024] (int)   padded class starts (%4==0)
//   [4096,   8192)   counts[1024] (int)   true class counts
//   [8192,  264192)  cnt_matrix[64][1000] (int)
//   [264192, ...)    rowlist[N + 4*NUM_C] (int)

// --- K1: cooperative hist + scan + scatter -------------------------------
__global__ __launch_bounds__(PRE_THREADS) void pre_kernel(
    const int4* __restrict__ labels4, int* __restrict__ cnt_matrix,
    int* __restrict__ starts, int* __restrict__ counts,
    int* __restrict__ rowlist, int rows_per_blk) {
    cg::grid_group grid = cg::this_grid();
    __shared__ int cnt[NUM_C];
    __shared__ int buf[1024];
    __shared__ int base_l[NUM_C];
    int t = threadIdx.x;
    int b = blockIdx.x;
    int n4pb = rows_per_blk / 4;               // 1024
    const int4* lb = labels4 + b * n4pb;

    // phase 1: per-block LDS histogram -> cnt_matrix (no global atomics)
    for (int i = t; i < NUM_C; i += PRE_THREADS) cnt[i] = 0;
    __syncthreads();
    for (int j = t; j < n4pb; j += PRE_THREADS) {
        int4 lab = lb[j];
        atomicAdd(&cnt[lab.x], 1);
        atomicAdd(&cnt[lab.y], 1);
        atomicAdd(&cnt[lab.z], 1);
        atomicAdd(&cnt[lab.w], 1);
    }
    __syncthreads();
    for (int i = t; i < NUM_C; i += PRE_THREADS)
        cnt_matrix[b * NUM_C + i] = cnt[i];

    grid.sync();

    // phase 2: column sums (total + prefix-before-me), padded scan, scatter
    int total = 0, before = 0;
    if (t < NUM_C) {
        for (int bb = 0; bb < PRE_BLOCKS; ++bb) {
            int v = cnt_matrix[bb * NUM_C + t];
            total += v;
            if (bb < b) before += v;
        }
    }
    int padsz = (t < NUM_C) ? ((total + 3) & ~3) : 0;
    buf[t] = padsz;
    for (int i = t; i < NUM_C; i += PRE_THREADS) cnt[i] = 0;  // re-zero for ranks
    __syncthreads();
    for (int off = 1; off < 1024; off <<= 1) {
        int x = (t >= off) ? buf[t - off] : 0;
        __syncthreads();
        buf[t] += x;
        __syncthreads();
    }
    int excl = buf[t] - padsz;                 // padded exclusive prefix
    if (t < NUM_C) base_l[t] = excl + before;
    if (b == 0 && t < NUM_C) {
        starts[t] = excl;
        counts[t] = total;
    }
    __syncthreads();

    // local rank within (block, class): 4 consecutive rows per thread
    int r = b * rows_per_blk + 4 * t;
    int4 lab = lb[t];                          // n4pb == PRE_THREADS
    int s0 = atomicAdd(&cnt[lab.x], 1);
    int s1 = atomicAdd(&cnt[lab.y], 1);
    int s2 = atomicAdd(&cnt[lab.z], 1);
    int s3 = atomicAdd(&cnt[lab.w], 1);
    __syncthreads();

    rowlist[base_l[lab.x] + s0] = r + 0;
    rowlist[base_l[lab.y] + s1] = r + 1;
    rowlist[base_l[lab.z] + s2] = r + 2;
    rowlist[base_l[lab.w] + s3] = r + 3;
}

// --- K2: gather-reduce, one block per class, int4 index loads ------------
// 512 threads = 4 row-slots x 128 float4 quads. Class start is 16B-aligned
// in rowlist, so each slot fetches its 4 row indices as one int4, with a
// one-iteration prefetch to hide index latency under feature loads.
__global__ __launch_bounds__(RED_THREADS, 8) void reduce_kernel(
    const f32x4* __restrict__ F4,
    const int* __restrict__ starts, const int* __restrict__ counts,
    const int* __restrict__ rowlist, float* __restrict__ out) {
    int c = blockIdx.x;
    int t = threadIdx.x;
    int slot = t >> 7;             // 0..3, wave-uniform
    int q = t & 127;               // float4 column index

    int start = starts[c];         // %4 == 0
    int cnt = counts[c];

    const int4* rl4 = (const int4*)(rowlist + start);
    f32x4 acc = {0.f, 0.f, 0.f, 0.f};

    int nIter = cnt >> 4;          // full 16-row groups
    int4 e = (nIter > 0) ? rl4[slot] : make_int4(0, 0, 0, 0);
    for (int it = 0; it < nIter; ++it) {
        int4 en = e;
        if (it + 1 < nIter) en = rl4[((it + 1) << 2) + slot];
        int r0 = __builtin_amdgcn_readfirstlane(e.x);
        int r1 = __builtin_amdgcn_readfirstlane(e.y);
        int r2 = __builtin_amdgcn_readfirstlane(e.z);
        int r3 = __builtin_amdgcn_readfirstlane(e.w);
        f32x4 v0 = F4[(size_t)r0 * (NUM_A / 4) + q];
        f32x4 v1 = F4[(size_t)r1 * (NUM_A / 4) + q];
        f32x4 v2 = F4[(size_t)r2 * (NUM_A / 4) + q];
        f32x4 v3 = F4[(size_t)r3 * (NUM_A / 4) + q];
        acc += (v0 + v1) + (v2 + v3);
        e = en;
    }
    for (int k = (nIter << 4) + slot; k < cnt; k += 4) {
        int r = __builtin_amdgcn_readfirstlane(rowlist[start + k]);
        acc += F4[(size_t)r * (NUM_A / 4) + q];
    }

    __shared__ f32x4 sbuf[3][128];
    if (slot > 0) sbuf[slot - 1][q] = acc;
    __syncthreads();
    if (slot == 0) {
        acc += (sbuf[0][q] + sbuf[1][q]) + sbuf[2][q];
        float inv = 1.0f / (float)(cnt > 0 ? cnt : 1);
        f32x4 res = acc * inv;
        ((f32x4*)out)[(size_t)c * (NUM_A / 4) + q] = res;
    }
}

extern "C" void kernel_launch(void* const* d_in, const int* in_sizes, int n_in,
                              void* d_out, int out_size, void* d_ws, size_t ws_size,
                              hipStream_t stream) {
    const float* features = (const float*)d_in[0];
    const int* labels = (const int*)d_in[1];
    float* out = (float*)d_out;
    int n = in_sizes[1];                    // 262144
    int rows_per_blk = n / PRE_BLOCKS;      // 4096

    char* ws = (char*)d_ws;
    int* starts     = (int*)(ws + 0);
    int* counts     = (int*)(ws + 4096);
    int* cnt_matrix = (int*)(ws + 8192);
    int* rowlist    = (int*)(ws + 8192 + PRE_BLOCKS * NUM_C * 4);

    const int4* labels4 = (const int4*)labels;
    void* args[] = {
        (void*)&labels4, (void*)&cnt_matrix, (void*)&starts,
        (void*)&counts, (void*)&rowlist, (void*)&rows_per_blk,
    };
    hipLaunchCooperativeKernel((void*)pre_kernel, dim3(PRE_BLOCKS),
                               dim3(PRE_THREADS), args, 0, stream);

    reduce_kernel<<<NUM_C, RED_THREADS, 0, stream>>>(
        (const f32x4*)features, starts, counts, rowlist, out);
}

// Round 9
// 116.937 us; speedup vs baseline: 1.2197x; 1.2197x over previous
//
#include <hip/hip_runtime.h>

#define NUM_C 1000
#define NUM_A 512
#define PRE_BLOCKS 64
#define PRE_THREADS 1024
#define RED_THREADS 512

typedef float f32x4 __attribute__((ext_vector_type(4)));

// Workspace layout (bytes):
//   [0,      4096)   starts[1024] (int)   padded class starts (%4==0)
//   [4096,   8192)   counts[1024] (int)   true class counts
//   [8192,  264192)  cnt_matrix[64][1000] (int)
//   [264192, ...)    rowlist[N + 4*NUM_C] (int)

// --- K1: per-block histogram, no global atomics --------------------------
__global__ __launch_bounds__(PRE_THREADS) void hist_kernel(
    const int4* __restrict__ labels4, int* __restrict__ cnt_matrix, int n4_per_blk) {
    __shared__ int cnt[NUM_C];
    int t = threadIdx.x;
    for (int i = t; i < NUM_C; i += PRE_THREADS) cnt[i] = 0;
    __syncthreads();
    int base = blockIdx.x * n4_per_blk;
    for (int j = t; j < n4_per_blk; j += PRE_THREADS) {
        int4 lab = labels4[base + j];
        atomicAdd(&cnt[lab.x], 1);
        atomicAdd(&cnt[lab.y], 1);
        atomicAdd(&cnt[lab.z], 1);
        atomicAdd(&cnt[lab.w], 1);
    }
    __syncthreads();
    int* dst = cnt_matrix + blockIdx.x * NUM_C;
    for (int i = t; i < NUM_C; i += PRE_THREADS) dst[i] = cnt[i];
}

// --- K2: scan (padded) + scatter, no global atomics ----------------------
__global__ __launch_bounds__(PRE_THREADS) void scan_scatter_kernel(
    const int4* __restrict__ labels4, const int* __restrict__ cnt_matrix,
    int* __restrict__ starts, int* __restrict__ counts,
    int* __restrict__ rowlist, int rows_per_blk) {
    __shared__ int buf[1024];
    __shared__ int cnt[NUM_C];
    __shared__ int base_l[NUM_C];
    int t = threadIdx.x;
    int b = blockIdx.x;

    // column sum over blocks: total and prefix-before-me (coalesced reads)
    int total = 0, before = 0;
    if (t < NUM_C) {
        for (int bb = 0; bb < PRE_BLOCKS; ++bb) {
            int v = cnt_matrix[bb * NUM_C + t];
            total += v;
            if (bb < b) before += v;
        }
    }
    int padsz = (t < NUM_C) ? ((total + 3) & ~3) : 0;   // pad to %4
    buf[t] = padsz;
    for (int i = t; i < NUM_C; i += PRE_THREADS) cnt[i] = 0;
    __syncthreads();

    // Hillis-Steele scan over padded class sizes
    for (int off = 1; off < 1024; off <<= 1) {
        int x = (t >= off) ? buf[t - off] : 0;
        __syncthreads();
        buf[t] += x;
        __syncthreads();
    }
    int excl = buf[t] - padsz;            // padded exclusive prefix (%4==0)
    if (t < NUM_C) base_l[t] = excl + before;
    if (b == 0 && t < NUM_C) {
        starts[t] = excl;
        counts[t] = total;
    }
    __syncthreads();

    // local rank within (block, class): 4 consecutive rows per thread
    int r = b * rows_per_blk + 4 * t;
    int4 lab = labels4[b * (rows_per_blk / 4) + t];
    int s0 = atomicAdd(&cnt[lab.x], 1);
    int s1 = atomicAdd(&cnt[lab.y], 1);
    int s2 = atomicAdd(&cnt[lab.z], 1);
    int s3 = atomicAdd(&cnt[lab.w], 1);
    __syncthreads();

    rowlist[base_l[lab.x] + s0] = r + 0;
    rowlist[base_l[lab.y] + s1] = r + 1;
    rowlist[base_l[lab.z] + s2] = r + 2;
    rowlist[base_l[lab.w] + s3] = r + 3;
}

// --- K3: gather-reduce, one block per class, branchless int4 index loads -
__global__ __launch_bounds__(RED_THREADS, 8) void reduce_kernel(
    const f32x4* __restrict__ F4,
    const int* __restrict__ starts, const int* __restrict__ counts,
    const int* __restrict__ rowlist, float* __restrict__ out) {
    int c = blockIdx.x;
    int t = threadIdx.x;
    int slot = t >> 7;             // 0..3, wave-uniform
    int q = t & 127;               // float4 column index

    int start = starts[c];         // %4 == 0 -> 16B-aligned int4 base
    int cnt = counts[c];

    const int4* rl4 = (const int4*)(rowlist + start);
    f32x4 acc = {0.f, 0.f, 0.f, 0.f};

    int nIter = cnt >> 4;          // full 16-row groups
    for (int it = 0; it < nIter; ++it) {
        int4 e = rl4[(it << 2) + slot];
        int r0 = __builtin_amdgcn_readfirstlane(e.x);
        int r1 = __builtin_amdgcn_readfirstlane(e.y);
        int r2 = __builtin_amdgcn_readfirstlane(e.z);
        int r3 = __builtin_amdgcn_readfirstlane(e.w);
        f32x4 v0 = F4[(size_t)r0 * (NUM_A / 4) + q];
        f32x4 v1 = F4[(size_t)r1 * (NUM_A / 4) + q];
        f32x4 v2 = F4[(size_t)r2 * (NUM_A / 4) + q];
        f32x4 v3 = F4[(size_t)r3 * (NUM_A / 4) + q];
        acc += (v0 + v1) + (v2 + v3);
    }
    for (int k = (nIter << 4) + slot; k < cnt; k += 4) {
        int r = __builtin_amdgcn_readfirstlane(rowlist[start + k]);
        acc += F4[(size_t)r * (NUM_A / 4) + q];
    }

    __shared__ f32x4 sbuf[3][128];
    if (slot > 0) sbuf[slot - 1][q] = acc;
    __syncthreads();
    if (slot == 0) {
        acc += (sbuf[0][q] + sbuf[1][q]) + sbuf[2][q];
        float inv = 1.0f / (float)(cnt > 0 ? cnt : 1);
        f32x4 res = acc * inv;
        ((f32x4*)out)[(size_t)c * (NUM_A / 4) + q] = res;
    }
}

extern "C" void kernel_launch(void* const* d_in, const int* in_sizes, int n_in,
                              void* d_out, int out_size, void* d_ws, size_t ws_size,
                              hipStream_t stream) {
    const float* features = (const float*)d_in[0];
    const int* labels = (const int*)d_in[1];
    float* out = (float*)d_out;
    int n = in_sizes[1];                    // 262144
    int n4_per_blk = (n / 4) / PRE_BLOCKS;  // 1024
    int rows_per_blk = n / PRE_BLOCKS;      // 4096

    char* ws = (char*)d_ws;
    int* starts     = (int*)(ws + 0);
    int* counts     = (int*)(ws + 4096);
    int* cnt_matrix = (int*)(ws + 8192);
    int* rowlist    = (int*)(ws + 8192 + PRE_BLOCKS * NUM_C * 4);

    hist_kernel<<<PRE_BLOCKS, PRE_THREADS, 0, stream>>>(
        (const int4*)labels, cnt_matrix, n4_per_blk);
    scan_scatter_kernel<<<PRE_BLOCKS, PRE_THREADS, 0, stream>>>(
        (const int4*)labels, cnt_matrix, starts, counts, rowlist, rows_per_blk);
    reduce_kernel<<<NUM_C, RED_THREADS, 0, stream>>>(
        (const f32x4*)features, starts, counts, rowlist, out);
}